// Round 11
// baseline (2031.714 us; speedup 1.0000x reference)
//
#include <hip/hip_runtime.h>

// Only the temporal (LSTM) branch of the reference reaches the output
// (h_gcn is dead). Per node:
//   xt_s = x[n, 52+s] * W_tp + b_tp          (rank-1, folded into A0/C0)
//   2-layer LSTM (H=32, T=12, torch gate order i,f,g,o)
//   out[n] = relu(h1 @ W_fc1 + b_fc1) @ W_fc2 + b_fc2
//
// v7 = v6 (4 waves cooperate on 64 nodes, j-split across waves) + OPAQUE
// REGISTER PINNING of the h-state.
//   Measured defect in v4/v6: for 256-thread blocks the allocator targets
//   the 8-waves/SIMD tier (VGPR=60) and gets there by folding the
//   h0[k]=snhA[...] copies back into per-use LDS re-reads (legal: the
//   values' only provenance is LDS) -> 2.7x VALU stream (1593 vs 593
//   us*CU), 1943 us. __launch_bounds__(BS,1) was ignored.
//   Fix: asm volatile("" : "+v"(h)) after each commit makes the values
//   opaque -> remat impossible -> h stays in VGPRs. Live ~105-125 fits
//   the 4-waves/SIMD tier (128) this allocator demonstrably uses.
// Structure: wave w computes gate rows j in [8w,8w+8). h-state replicated
// in registers; c-state partitioned in LDS columns (owner-only); new-h
// double-buffered in LDS (snhA/snhB), one barrier per layer. Weights via
// SGPR-uniform s_load (jbase pinned by readfirstlane).
// Expect VGPR ~104-128 -> 4 waves/SIMD; LDS 32KB -> 4 blocks/CU.

#define TSTEPS 12
#define NPB 64               // nodes per block
#define NW 4                 // waves per block
#define BS (NPB * NW)        // 256 threads
#define NJ (32 / NW)         // 8 gate-rows per wave

__device__ __forceinline__ float fsig(float x) {
    float e = __expf(-x);                      // v_exp path; e in [0, inf)
    return __builtin_amdgcn_rcpf(1.0f + e);    // 1/(1+e), ~1 ulp
}

__device__ __forceinline__ float ftanh(float x) {
    float ax = fabsf(x);
    float e = __expf(-2.0f * ax);              // in (0,1], no overflow
    float r = (1.0f - e) * __builtin_amdgcn_rcpf(1.0f + e);
    return x < 0.0f ? -r : r;
}

// Fold layer-0 input matmul:
//   A0[r] = dot(Wih0[r,:], W_tp)          (scalar per gate row)
//   C0[r] = dot(Wih0[r,:], b_tp) + bih0[r] + bhh0[r]
//   C1[r] = bih1[r] + bhh1[r]
// ws layout: [0:128) A0, [128:256) C0, [256:384) C1
__global__ void precomp_kernel(const float* __restrict__ Wih0,
                               const float* __restrict__ Wtp,
                               const float* __restrict__ btp,
                               const float* __restrict__ bih0,
                               const float* __restrict__ bhh0,
                               const float* __restrict__ bih1,
                               const float* __restrict__ bhh1,
                               float* __restrict__ ws) {
    int r = threadIdx.x;   // 0..127
    if (r < 128) {
        float a = 0.0f, c = 0.0f;
#pragma unroll
        for (int k = 0; k < 16; ++k) {
            float w = Wih0[r * 16 + k];
            a += w * Wtp[k];
            c += w * btp[k];
        }
        ws[r]       = a;
        ws[128 + r] = c + bih0[r] + bhh0[r];
        ws[256 + r] = bih1[r] + bhh1[r];
    }
}

__global__ __launch_bounds__(BS, 1) void lstm_kernel(
    const float* __restrict__ x,
    const float* __restrict__ Whh0,   // [128,32]
    const float* __restrict__ Wih1,   // [128,32]
    const float* __restrict__ Whh1,   // [128,32]
    const float* __restrict__ Wfc1,   // [32,16]
    const float* __restrict__ bfc1,   // [16]
    const float* __restrict__ Wfc2,   // [16]
    const float* __restrict__ bfc2,   // [1]
    const float* __restrict__ pre,    // [384] from precomp
    float* __restrict__ out, int N)
{
    // c-state: partitioned, each wave owns its j-range columns (owner-only
    // access, no sync). snhA/snhB: h staged by producers, read by ALL
    // threads. Index [j*NPB + node]: consecutive lanes -> consecutive
    // banks (2 lanes/bank for wave64 = free).
    __shared__ float sc0 [32 * NPB];
    __shared__ float sc1 [32 * NPB];
    __shared__ float snhA[32 * NPB];   // layer-0 new h
    __shared__ float snhB[32 * NPB];   // layer-1 new h

    const int tid  = threadIdx.x;
    const int node = tid & (NPB - 1);
    // Wave-uniform gate-row base, FORCED into an SGPR so weight addresses
    // take the scalar-load (K$) path instead of per-lane vector loads.
    const int jbase = __builtin_amdgcn_readfirstlane((tid >> 6) * NJ);
    const int n  = blockIdx.x * NPB + node;
    const int nn = (n < N) ? n : (N > 0 ? N - 1 : 0);
    const float* xr = x + (size_t)nn * 64 + 52;   // last 12 features

    float h0[32], h1[32];
#pragma unroll
    for (int k = 0; k < 32; ++k) { h0[k] = 0.0f; h1[k] = 0.0f; }
#pragma unroll
    for (int jj = 0; jj < NJ; ++jj) {             // owner-only init, no sync
        sc0[(jbase + jj) * NPB + node] = 0.0f;
        sc1[(jbase + jj) * NPB + node] = 0.0f;
    }

#pragma unroll 1
    for (int t = 0; t < TSTEPS; ++t) {
        const float xval = xr[t];

        // ---------------- layer 0 (this wave's 8 gate rows) -------------
#pragma unroll 1
        for (int jj = 0; jj < NJ; ++jj) {
            const int j = jbase + jj;             // SGPR-resident
            float gi = pre[128 + j] + xval * pre[j];
            float gf = pre[160 + j] + xval * pre[32 + j];
            float gg = pre[192 + j] + xval * pre[64 + j];
            float go = pre[224 + j] + xval * pre[96 + j];
            const float* w = Whh0 + j * 32;       // rows j, j+32, j+64, j+96
#pragma unroll
            for (int k = 0; k < 32; ++k) {
                const float hk = h0[k];
                gi += w[k]        * hk;
                gf += w[1024 + k] * hk;
                gg += w[2048 + k] * hk;
                go += w[3072 + k] * hk;
            }
            const int ci = j * NPB + node;
            const float cc = fsig(gf) * sc0[ci] + fsig(gi) * ftanh(gg);
            sc0[ci]  = cc;
            snhA[ci] = fsig(go) * ftanh(cc);
        }
        __syncthreads();                           // snhA complete
#pragma unroll
        for (int k = 0; k < 32; ++k) h0[k] = snhA[k * NPB + node];
        // PIN: make h0 opaque (no LDS provenance) so the allocator cannot
        // remat it as per-use ds_reads (the v4/v6 2.7x-stream defect).
#pragma unroll
        for (int k = 0; k < 32; ++k) asm volatile("" : "+v"(h0[k]));

        // ---------------- layer 1 (this wave's 8 gate rows) -------------
#pragma unroll 1
        for (int jj = 0; jj < NJ; ++jj) {
            const int j = jbase + jj;
            float gi = pre[256 + j];
            float gf = pre[288 + j];
            float gg = pre[320 + j];
            float go = pre[352 + j];
            const float* wi = Wih1 + j * 32;
            const float* wh = Whh1 + j * 32;
#pragma unroll
            for (int k = 0; k < 32; ++k) {
                const float ak = h0[k];
                const float bk = h1[k];
                gi += wi[k]        * ak + wh[k]        * bk;
                gf += wi[1024 + k] * ak + wh[1024 + k] * bk;
                gg += wi[2048 + k] * ak + wh[2048 + k] * bk;
                go += wi[3072 + k] * ak + wh[3072 + k] * bk;
            }
            const int ci = j * NPB + node;
            const float cc = fsig(gf) * sc1[ci] + fsig(gi) * ftanh(gg);
            sc1[ci]  = cc;
            snhB[ci] = fsig(go) * ftanh(cc);
        }
        __syncthreads();                           // snhB complete; also
                                                   // fences snhA reads vs
                                                   // next-t layer-0 writes
#pragma unroll
        for (int k = 0; k < 32; ++k) h1[k] = snhB[k * NPB + node];
#pragma unroll
        for (int k = 0; k < 32; ++k) asm volatile("" : "+v"(h1[k]));
        // snhB reads vs next-t layer-1 writes are fenced by the next
        // iteration's first barrier.
    }

    // epilogue: relu(h1 @ Wfc1 + bfc1) @ Wfc2 + bfc2 — wave 0 only
    // (h1 is replicated in every thread's registers)
    if (tid < NPB) {
        float acc = bfc2[0];
#pragma unroll 1
        for (int m = 0; m < 16; ++m) {
            float a = bfc1[m];
#pragma unroll
            for (int k = 0; k < 32; ++k) a += h1[k] * Wfc1[k * 16 + m];
            acc += fmaxf(a, 0.0f) * Wfc2[m];
        }
        if (n < N) out[n] = acc;
    }
}

extern "C" void kernel_launch(void* const* d_in, const int* in_sizes, int n_in,
                              void* d_out, int out_size, void* d_ws, size_t ws_size,
                              hipStream_t stream) {
    (void)n_in; (void)out_size; (void)ws_size;
    // setup_inputs() order:
    // 0 x, 1 edge_index, 2 W_fp, 3 b_fp, 4 W_g1, 5 b_g1, 6 W_g2, 7 b_g2,
    // 8 W_g3, 9 b_g3, 10 W_tp, 11 b_tp, 12 Wih0, 13 Whh0, 14 bih0, 15 bhh0,
    // 16 Wih1, 17 Whh1, 18 bih1, 19 bhh1, 20 W_fc1, 21 b_fc1, 22 W_fc2, 23 b_fc2
    const float* x    = (const float*)d_in[0];
    const float* Wtp  = (const float*)d_in[10];
    const float* btp  = (const float*)d_in[11];
    const float* Wih0 = (const float*)d_in[12];
    const float* Whh0 = (const float*)d_in[13];
    const float* bih0 = (const float*)d_in[14];
    const float* bhh0 = (const float*)d_in[15];
    const float* Wih1 = (const float*)d_in[16];
    const float* Whh1 = (const float*)d_in[17];
    const float* bih1 = (const float*)d_in[18];
    const float* bhh1 = (const float*)d_in[19];
    const float* Wfc1 = (const float*)d_in[20];
    const float* bfc1 = (const float*)d_in[21];
    const float* Wfc2 = (const float*)d_in[22];
    const float* bfc2 = (const float*)d_in[23];

    float* out = (float*)d_out;
    float* pre = (float*)d_ws;   // 384 floats

    const int N = in_sizes[0] / 64;

    precomp_kernel<<<1, 128, 0, stream>>>(Wih0, Wtp, btp, bih0, bhh0, bih1, bhh1, pre);
    lstm_kernel<<<(N + NPB - 1) / NPB, BS, 0, stream>>>(
        x, Whh0, Wih1, Whh1, Wfc1, bfc1, Wfc2, bfc2, pre, out, N);
}

// Round 12
// 1458.499 us; speedup vs baseline: 1.3930x; 1.3930x over previous
//
#include <hip/hip_runtime.h>

// Only the temporal (LSTM) branch of the reference reaches the output
// (h_gcn is dead). Per node:
//   xt_s = x[n, 52+s] * W_tp + b_tp          (rank-1, folded into A0/C0)
//   2-layer LSTM (H=32, T=12, torch gate order i,f,g,o)
//   out[n] = relu(h1 @ W_fc1 + b_fc1) @ W_fc2 + b_fc2
//
// v8 = v5's quad k-split with the loop nest inverted to avoid v5's spill.
//   - v5 (fully unrolled j-loops) let the pre-RA scheduler hoist ~128
//     float4 LDS loads -> 33 GB scratch traffic at VGPR=128.
//   - v8: OUTER jj 0..7 unrolled (static -> c0r[jj]/hn[jj] in registers),
//     INNER g 0..3 '#pragma unroll 1' -> only one gate-row's weights
//     (8-16 float4) in flight; peak live ~115 regs.
//   - State provenance is arithmetic+shfl (never LDS) -> the v4/v6/v7
//     remat pathology (h re-read from LDS at VGPR=60) cannot apply.
// 4 lanes per node (s=tid&3 owns k-slice [8s,8s+8)); per-j 8-wide partial
// dots + quad butterfly (__shfl_xor 1,2); owner lane updates c/hn; commit
// hn->h is a pure register copy in slice layout. Weights (48 KB) staged
// once in LDS, quad-broadcast ds_read_b128 (4 distinct 32B-apart addrs
// per instr -> conflict-free). Grid = 6250 waves (4x v1's TLP).

#define TSTEPS 12
#define BS 512               // 8 waves per block
#define NPB (BS / 4)         // 128 nodes per block

__device__ __forceinline__ float fsig(float x) {
    float e = __expf(-x);                      // v_exp path; e in [0, inf)
    return __builtin_amdgcn_rcpf(1.0f + e);    // 1/(1+e), ~1 ulp
}

__device__ __forceinline__ float ftanh(float x) {
    float ax = fabsf(x);
    float e = __expf(-2.0f * ax);              // in (0,1], no overflow
    float r = (1.0f - e) * __builtin_amdgcn_rcpf(1.0f + e);
    return x < 0.0f ? -r : r;
}

// Fold layer-0 input matmul:
//   A0[r] = dot(Wih0[r,:], W_tp)          (scalar per gate row)
//   C0[r] = dot(Wih0[r,:], b_tp) + bih0[r] + bhh0[r]
//   C1[r] = bih1[r] + bhh1[r]
// ws layout: [0:128) A0, [128:256) C0, [256:384) C1
__global__ void precomp_kernel(const float* __restrict__ Wih0,
                               const float* __restrict__ Wtp,
                               const float* __restrict__ btp,
                               const float* __restrict__ bih0,
                               const float* __restrict__ bhh0,
                               const float* __restrict__ bih1,
                               const float* __restrict__ bhh1,
                               float* __restrict__ ws) {
    int r = threadIdx.x;   // 0..127
    if (r < 128) {
        float a = 0.0f, c = 0.0f;
#pragma unroll
        for (int k = 0; k < 16; ++k) {
            float w = Wih0[r * 16 + k];
            a += w * Wtp[k];
            c += w * btp[k];
        }
        ws[r]       = a;
        ws[128 + r] = c + bih0[r] + bhh0[r];
        ws[256 + r] = bih1[r] + bhh1[r];
    }
}

__device__ __forceinline__ float dot8(const float4 a0, const float4 a1,
                                      const float h[8]) {
    return a0.x*h[0] + a0.y*h[1] + a0.z*h[2] + a0.w*h[3]
         + a1.x*h[4] + a1.y*h[5] + a1.z*h[6] + a1.w*h[7];
}

__global__ __launch_bounds__(BS) void lstm_kernel(
    const float* __restrict__ x,
    const float* __restrict__ Whh0,   // [128,32]
    const float* __restrict__ Wih1,   // [128,32]
    const float* __restrict__ Whh1,   // [128,32]
    const float* __restrict__ Wfc1,   // [32,16]
    const float* __restrict__ bfc1,   // [16]
    const float* __restrict__ Wfc2,   // [16]
    const float* __restrict__ bfc2,   // [1]
    const float* __restrict__ pre,    // [384] from precomp
    float* __restrict__ out, int N)
{
    // 48 KB weights: [0:4096) Whh0, [4096:8192) Wih1, [8192:12288) Whh1,
    // all row-major [128][32].
    __shared__ __align__(16) float sW[12288];

    const int tid = threadIdx.x;
#pragma unroll
    for (int i = 0; i < 8; ++i) sW[i * BS + tid]        = Whh0[i * BS + tid];
#pragma unroll
    for (int i = 0; i < 8; ++i) sW[4096 + i * BS + tid] = Wih1[i * BS + tid];
#pragma unroll
    for (int i = 0; i < 8; ++i) sW[8192 + i * BS + tid] = Whh1[i * BS + tid];
    __syncthreads();                    // only barrier in the kernel

    const int s    = tid & 3;           // k-slice 0..3
    const int node = tid >> 2;          // 0..127 within block
    const int so8  = s * 8;             // slice base (floats)
    const int n  = blockIdx.x * NPB + node;
    const int nn = (n < N) ? n : (N > 0 ? N - 1 : 0);
    const float* xr = x + (size_t)nn * 64 + 52;   // last 12 features

    // Per-lane slices: h0/h1/c0/c1 for k,j in [8s, 8s+8). All indices
    // STATIC (outer jj unrolled) -> registers, no scratch, no LDS state.
    float h0r[8], h1r[8], c0r[8], c1r[8], hn[8];
#pragma unroll
    for (int k = 0; k < 8; ++k) { h0r[k] = 0.0f; h1r[k] = 0.0f; c0r[k] = 0.0f; c1r[k] = 0.0f; }

#pragma unroll 1
    for (int t = 0; t < TSTEPS; ++t) {
        const float xval = xr[t];

        // ---------------- layer 0 ----------------
#pragma unroll
        for (int jj = 0; jj < 8; ++jj) {          // static
#pragma unroll 1
            for (int g = 0; g < 4; ++g) {         // one j's weights live
                const int j = g * 8 + jj;
                const float* wi = &sW[(j      ) * 32 + so8];
                const float* wf = &sW[(j +  32) * 32 + so8];
                const float* wg = &sW[(j +  64) * 32 + so8];
                const float* wo = &sW[(j +  96) * 32 + so8];
                float pi = dot8(((const float4*)wi)[0], ((const float4*)wi)[1], h0r);
                float pf = dot8(((const float4*)wf)[0], ((const float4*)wf)[1], h0r);
                float pg = dot8(((const float4*)wg)[0], ((const float4*)wg)[1], h0r);
                float po = dot8(((const float4*)wo)[0], ((const float4*)wo)[1], h0r);
                // quad reduce (stays within the node's 4 lanes)
                pi += __shfl_xor(pi, 1); pi += __shfl_xor(pi, 2);
                pf += __shfl_xor(pf, 1); pf += __shfl_xor(pf, 2);
                pg += __shfl_xor(pg, 1); pg += __shfl_xor(pg, 2);
                po += __shfl_xor(po, 1); po += __shfl_xor(po, 2);
                const float gi = pi + pre[128 + j] + xval * pre[j];
                const float gf = pf + pre[160 + j] + xval * pre[32 + j];
                const float gg = pg + pre[192 + j] + xval * pre[64 + j];
                const float go = po + pre[224 + j] + xval * pre[96 + j];
                // non-owners compute garbage cc/hh (stale c) and discard
                const float cc = fsig(gf) * c0r[jj] + fsig(gi) * ftanh(gg);
                const float hh = fsig(go) * ftanh(cc);
                if (s == g) { c0r[jj] = cc; hn[jj] = hh; }
            }
        }
#pragma unroll
        for (int k = 0; k < 8; ++k) h0r[k] = hn[k];   // commit new h0 (regs)

        // ---------------- layer 1 ----------------
#pragma unroll
        for (int jj = 0; jj < 8; ++jj) {          // static
#pragma unroll 1
            for (int g = 0; g < 4; ++g) {         // one j's weights live
                const int j = g * 8 + jj;
                const float* ai = &sW[4096 + (j      ) * 32 + so8];
                const float* af = &sW[4096 + (j +  32) * 32 + so8];
                const float* ag = &sW[4096 + (j +  64) * 32 + so8];
                const float* ao = &sW[4096 + (j +  96) * 32 + so8];
                const float* bi = &sW[8192 + (j      ) * 32 + so8];
                const float* bf = &sW[8192 + (j +  32) * 32 + so8];
                const float* bg = &sW[8192 + (j +  64) * 32 + so8];
                const float* bo = &sW[8192 + (j +  96) * 32 + so8];
                float pi = dot8(((const float4*)ai)[0], ((const float4*)ai)[1], h0r)
                         + dot8(((const float4*)bi)[0], ((const float4*)bi)[1], h1r);
                float pf = dot8(((const float4*)af)[0], ((const float4*)af)[1], h0r)
                         + dot8(((const float4*)bf)[0], ((const float4*)bf)[1], h1r);
                float pg = dot8(((const float4*)ag)[0], ((const float4*)ag)[1], h0r)
                         + dot8(((const float4*)bg)[0], ((const float4*)bg)[1], h1r);
                float po = dot8(((const float4*)ao)[0], ((const float4*)ao)[1], h0r)
                         + dot8(((const float4*)bo)[0], ((const float4*)bo)[1], h1r);
                pi += __shfl_xor(pi, 1); pi += __shfl_xor(pi, 2);
                pf += __shfl_xor(pf, 1); pf += __shfl_xor(pf, 2);
                pg += __shfl_xor(pg, 1); pg += __shfl_xor(pg, 2);
                po += __shfl_xor(po, 1); po += __shfl_xor(po, 2);
                const float gi = pi + pre[256 + j];
                const float gf = pf + pre[288 + j];
                const float gg = pg + pre[320 + j];
                const float go = po + pre[352 + j];
                const float cc = fsig(gf) * c1r[jj] + fsig(gi) * ftanh(gg);
                const float hh = fsig(go) * ftanh(cc);
                if (s == g) { c1r[jj] = cc; hn[jj] = hh; }
            }
        }
#pragma unroll
        for (int k = 0; k < 8; ++k) h1r[k] = hn[k];   // commit new h1 (regs)
    }

    // epilogue: relu(h1 @ Wfc1 + bfc1) @ Wfc2 + bfc2 (h1 sliced over quad)
    float am[16];
#pragma unroll
    for (int m = 0; m < 16; ++m) am[m] = 0.0f;
#pragma unroll 1
    for (int kk = 0; kk < 8; ++kk) {
        const float* row = Wfc1 + (size_t)(so8 + kk) * 16;
        const float4 r0 = ((const float4*)row)[0];
        const float4 r1 = ((const float4*)row)[1];
        const float4 r2 = ((const float4*)row)[2];
        const float4 r3 = ((const float4*)row)[3];
        const float hv = h1r[kk];
        am[ 0] += r0.x*hv; am[ 1] += r0.y*hv; am[ 2] += r0.z*hv; am[ 3] += r0.w*hv;
        am[ 4] += r1.x*hv; am[ 5] += r1.y*hv; am[ 6] += r1.z*hv; am[ 7] += r1.w*hv;
        am[ 8] += r2.x*hv; am[ 9] += r2.y*hv; am[10] += r2.z*hv; am[11] += r2.w*hv;
        am[12] += r3.x*hv; am[13] += r3.y*hv; am[14] += r3.z*hv; am[15] += r3.w*hv;
    }
    float acc = bfc2[0];
#pragma unroll
    for (int m = 0; m < 16; ++m) {
        float a = am[m];
        a += __shfl_xor(a, 1); a += __shfl_xor(a, 2);
        acc += fmaxf(a + bfc1[m], 0.0f) * Wfc2[m];
    }
    if (s == 0 && n < N) out[n] = acc;
}

extern "C" void kernel_launch(void* const* d_in, const int* in_sizes, int n_in,
                              void* d_out, int out_size, void* d_ws, size_t ws_size,
                              hipStream_t stream) {
    (void)n_in; (void)out_size; (void)ws_size;
    // setup_inputs() order:
    // 0 x, 1 edge_index, 2 W_fp, 3 b_fp, 4 W_g1, 5 b_g1, 6 W_g2, 7 b_g2,
    // 8 W_g3, 9 b_g3, 10 W_tp, 11 b_tp, 12 Wih0, 13 Whh0, 14 bih0, 15 bhh0,
    // 16 Wih1, 17 Whh1, 18 bih1, 19 bhh1, 20 W_fc1, 21 b_fc1, 22 W_fc2, 23 b_fc2
    const float* x    = (const float*)d_in[0];
    const float* Wtp  = (const float*)d_in[10];
    const float* btp  = (const float*)d_in[11];
    const float* Wih0 = (const float*)d_in[12];
    const float* Whh0 = (const float*)d_in[13];
    const float* bih0 = (const float*)d_in[14];
    const float* bhh0 = (const float*)d_in[15];
    const float* Wih1 = (const float*)d_in[16];
    const float* Whh1 = (const float*)d_in[17];
    const float* bih1 = (const float*)d_in[18];
    const float* bhh1 = (const float*)d_in[19];
    const float* Wfc1 = (const float*)d_in[20];
    const float* bfc1 = (const float*)d_in[21];
    const float* Wfc2 = (const float*)d_in[22];
    const float* bfc2 = (const float*)d_in[23];

    float* out = (float*)d_out;
    float* pre = (float*)d_ws;   // 384 floats

    const int N = in_sizes[0] / 64;

    precomp_kernel<<<1, 128, 0, stream>>>(Wih0, Wtp, btp, bih0, bhh0, bih1, bhh1, pre);
    lstm_kernel<<<(N + NPB - 1) / NPB, BS, 0, stream>>>(
        x, Whh0, Wih1, Whh1, Wfc1, bfc1, Wfc2, bfc2, pre, out, N);
}

// Round 15
// 1261.998 us; speedup vs baseline: 1.6099x; 1.1557x over previous
//
#include <hip/hip_runtime.h>

// Only the temporal (LSTM) branch of the reference reaches the output
// (h_gcn is dead). Per node:
//   xt_s = x[n, 52+s] * W_tp + b_tp          (rank-1, folded into A0/C0)
//   2-layer LSTM (H=32, T=12, torch gate order i,f,g,o)
//   out[n] = relu(h1 @ W_fc1 + b_fc1) @ W_fc2 + b_fc2
//
// v9 = v8 (quad k-split, 4 lanes/node, state in regs, weights in LDS)
// with the 4x-redundant gate-finish eliminated via REDUCE-SCATTER:
//   - v8: per (jj,g) all 4 lanes butterfly to the full sum and all 4
//     compute exp/tanh gate-finish; 3 of 4 discard (if s==g). ~30% of
//     issue cycles wasted (trans-heavy).
//   - v9: per jj each lane computes partials for all 4 g (FMA count
//     unchanged, p[gate][g] static via full unroll + sched_barrier(0)
//     per g to stop load hoisting, the v5 spill cause), then a 2-stage
//     reduce-scatter (xor2, xor1) lands j=s*8+jj's sums on the owner.
//     Gate-finish runs ONCE per j; no own-select.
//   - precomp repacks biases per-j: ws[j*8]={A0 quad, C0 quad},
//     ws[256+j*4]={C1 quad} -> 2-3 float4 loads per jj for the finish.
// Spill tell-tale: hbm_bytes >> 10 MB. I$ tell-tale: low VALUBusy, no
// spill, dur flat.
// (2nd resubmission: rounds 13 and 14 both failed on GPU acquisition.)

#define TSTEPS 12
#define BS 512               // 8 waves per block
#define NPB (BS / 4)         // 128 nodes per block

__device__ __forceinline__ float fsig(float x) {
    float e = __expf(-x);                      // v_exp path; e in [0, inf)
    return __builtin_amdgcn_rcpf(1.0f + e);    // 1/(1+e), ~1 ulp
}

__device__ __forceinline__ float ftanh(float x) {
    float ax = fabsf(x);
    float e = __expf(-2.0f * ax);              // in (0,1], no overflow
    float r = (1.0f - e) * __builtin_amdgcn_rcpf(1.0f + e);
    return x < 0.0f ? -r : r;
}

// Repacked fold of layer-0 input matmul + biases, per OUTPUT j:
//   ws[j*8 + {0..3}] = A0 for gates i,f,g,o of j   (A0[r]=dot(Wih0[r,:],W_tp))
//   ws[j*8 + {4..7}] = C0 for gates i,f,g,o of j   (C0[r]=dot(Wih0[r,:],b_tp)+bih0[r]+bhh0[r])
//   ws[256 + j*4 + {0..3}] = C1 gates i,f,g,o      (bih1[r]+bhh1[r])
// where r = gate*32 + j.
__global__ void precomp_kernel(const float* __restrict__ Wih0,
                               const float* __restrict__ Wtp,
                               const float* __restrict__ btp,
                               const float* __restrict__ bih0,
                               const float* __restrict__ bhh0,
                               const float* __restrict__ bih1,
                               const float* __restrict__ bhh1,
                               float* __restrict__ ws) {
    int r = threadIdx.x;   // 0..127
    if (r < 128) {
        float a = 0.0f, c = 0.0f;
#pragma unroll
        for (int k = 0; k < 16; ++k) {
            float w = Wih0[r * 16 + k];
            a += w * Wtp[k];
            c += w * btp[k];
        }
        const int g4 = r >> 5;          // gate 0..3 (i,f,g,o)
        const int j  = r & 31;          // output index
        ws[j * 8 + g4]       = a;
        ws[j * 8 + 4 + g4]   = c + bih0[r] + bhh0[r];
        ws[256 + j * 4 + g4] = bih1[r] + bhh1[r];
    }
}

__device__ __forceinline__ float dot8(const float4 a0, const float4 a1,
                                      const float h[8]) {
    return a0.x*h[0] + a0.y*h[1] + a0.z*h[2] + a0.w*h[3]
         + a1.x*h[4] + a1.y*h[5] + a1.z*h[6] + a1.w*h[7];
}

// Reduce-scatter over a quad: inputs v0..v3 (per-g partials, all lanes),
// returns sum over the 4 lanes of v_s (s = lane&3). hi2=(s&2), hi1=(s&1).
__device__ __forceinline__ float rs4(float v0, float v1, float v2, float v3,
                                     bool hi2, bool hi1) {
    float sa = hi2 ? v0 : v2;     // give away first-of-other-pair
    float ka = hi2 ? v2 : v0;     // keep first-of-own-pair (g = s&2)
    float sb = hi2 ? v1 : v3;
    float kb = hi2 ? v3 : v1;     // g = (s&2)+1
    float u0 = ka + __shfl_xor(sa, 2);
    float u1 = kb + __shfl_xor(sb, 2);
    float sc = hi1 ? u0 : u1;
    float kc = hi1 ? u1 : u0;     // g = s
    return kc + __shfl_xor(sc, 1);
}

__global__ __launch_bounds__(BS) void lstm_kernel(
    const float* __restrict__ x,
    const float* __restrict__ Whh0,   // [128,32]
    const float* __restrict__ Wih1,   // [128,32]
    const float* __restrict__ Whh1,   // [128,32]
    const float* __restrict__ Wfc1,   // [32,16]
    const float* __restrict__ bfc1,   // [16]
    const float* __restrict__ Wfc2,   // [16]
    const float* __restrict__ bfc2,   // [1]
    const float* __restrict__ pre,    // [384] from precomp (repacked)
    float* __restrict__ out, int N)
{
    // 48 KB weights: [0:4096) Whh0, [4096:8192) Wih1, [8192:12288) Whh1,
    // all row-major [128][32].
    __shared__ __align__(16) float sW[12288];

    const int tid = threadIdx.x;
#pragma unroll
    for (int i = 0; i < 8; ++i) sW[i * BS + tid]        = Whh0[i * BS + tid];
#pragma unroll
    for (int i = 0; i < 8; ++i) sW[4096 + i * BS + tid] = Wih1[i * BS + tid];
#pragma unroll
    for (int i = 0; i < 8; ++i) sW[8192 + i * BS + tid] = Whh1[i * BS + tid];
    __syncthreads();                    // only barrier in the kernel

    const int s    = tid & 3;           // k-slice / j-group 0..3
    const int node = tid >> 2;          // 0..127 within block
    const int so8  = s * 8;             // slice base (floats)
    const bool hi2 = (s & 2) != 0;
    const bool hi1 = (s & 1) != 0;
    const int n  = blockIdx.x * NPB + node;
    const int nn = (n < N) ? n : (N > 0 ? N - 1 : 0);
    const float* xr = x + (size_t)nn * 64 + 52;   // last 12 features

    // Per-lane slices: h/c for k,j in [8s, 8s+8). All indices STATIC.
    float h0r[8], h1r[8], c0r[8], c1r[8], hn[8];
#pragma unroll
    for (int k = 0; k < 8; ++k) { h0r[k] = 0.0f; h1r[k] = 0.0f; c0r[k] = 0.0f; c1r[k] = 0.0f; }

#pragma unroll 1
    for (int t = 0; t < TSTEPS; ++t) {
        const float xval = xr[t];

        // ---------------- layer 0 ----------------
#pragma unroll
        for (int jj = 0; jj < 8; ++jj) {          // static
            const int jown = so8 + jj;            // this lane's output j
            float pI[4], pF[4], pG[4], pO[4];
#pragma unroll
            for (int g = 0; g < 4; ++g) {         // partials for all 4 j's
                const int j = g * 8 + jj;
                const float* wi = &sW[(j      ) * 32 + so8];
                const float* wf = &sW[(j +  32) * 32 + so8];
                const float* wg = &sW[(j +  64) * 32 + so8];
                const float* wo = &sW[(j +  96) * 32 + so8];
                pI[g] = dot8(((const float4*)wi)[0], ((const float4*)wi)[1], h0r);
                pF[g] = dot8(((const float4*)wf)[0], ((const float4*)wf)[1], h0r);
                pG[g] = dot8(((const float4*)wg)[0], ((const float4*)wg)[1], h0r);
                pO[g] = dot8(((const float4*)wo)[0], ((const float4*)wo)[1], h0r);
                __builtin_amdgcn_sched_barrier(0);  // cap load window (v5 fix)
            }
            const float SI = rs4(pI[0], pI[1], pI[2], pI[3], hi2, hi1);
            const float SF = rs4(pF[0], pF[1], pF[2], pF[3], hi2, hi1);
            const float SG = rs4(pG[0], pG[1], pG[2], pG[3], hi2, hi1);
            const float SO = rs4(pO[0], pO[1], pO[2], pO[3], hi2, hi1);
            // gate-finish ONCE, on the owner lane's own j
            const float4 pA = ((const float4*)pre)[jown * 2];       // A0 quad
            const float4 pC = ((const float4*)pre)[jown * 2 + 1];   // C0 quad
            const float gi = SI + pC.x + xval * pA.x;
            const float gf = SF + pC.y + xval * pA.y;
            const float gG = SG + pC.z + xval * pA.z;
            const float go = SO + pC.w + xval * pA.w;
            const float cc = fsig(gf) * c0r[jj] + fsig(gi) * ftanh(gG);
            c0r[jj] = cc;
            hn[jj]  = fsig(go) * ftanh(cc);
        }
#pragma unroll
        for (int k = 0; k < 8; ++k) h0r[k] = hn[k];   // commit new h0 (regs)

        // ---------------- layer 1 ----------------
#pragma unroll
        for (int jj = 0; jj < 8; ++jj) {          // static
            const int jown = so8 + jj;
            float pI[4], pF[4], pG[4], pO[4];
#pragma unroll
            for (int g = 0; g < 4; ++g) {
                const int j = g * 8 + jj;
                {   // a-chunk: Wih1 . h0
                    const float* ai = &sW[4096 + (j      ) * 32 + so8];
                    const float* af = &sW[4096 + (j +  32) * 32 + so8];
                    const float* ag = &sW[4096 + (j +  64) * 32 + so8];
                    const float* ao = &sW[4096 + (j +  96) * 32 + so8];
                    pI[g] = dot8(((const float4*)ai)[0], ((const float4*)ai)[1], h0r);
                    pF[g] = dot8(((const float4*)af)[0], ((const float4*)af)[1], h0r);
                    pG[g] = dot8(((const float4*)ag)[0], ((const float4*)ag)[1], h0r);
                    pO[g] = dot8(((const float4*)ao)[0], ((const float4*)ao)[1], h0r);
                }
                __builtin_amdgcn_sched_barrier(0);
                {   // b-chunk: Whh1 . h1
                    const float* bi = &sW[8192 + (j      ) * 32 + so8];
                    const float* bf = &sW[8192 + (j +  32) * 32 + so8];
                    const float* bg = &sW[8192 + (j +  64) * 32 + so8];
                    const float* bo = &sW[8192 + (j +  96) * 32 + so8];
                    pI[g] += dot8(((const float4*)bi)[0], ((const float4*)bi)[1], h1r);
                    pF[g] += dot8(((const float4*)bf)[0], ((const float4*)bf)[1], h1r);
                    pG[g] += dot8(((const float4*)bg)[0], ((const float4*)bg)[1], h1r);
                    pO[g] += dot8(((const float4*)bo)[0], ((const float4*)bo)[1], h1r);
                }
                __builtin_amdgcn_sched_barrier(0);
            }
            const float SI = rs4(pI[0], pI[1], pI[2], pI[3], hi2, hi1);
            const float SF = rs4(pF[0], pF[1], pF[2], pF[3], hi2, hi1);
            const float SG = rs4(pG[0], pG[1], pG[2], pG[3], hi2, hi1);
            const float SO = rs4(pO[0], pO[1], pO[2], pO[3], hi2, hi1);
            const float4 pD = ((const float4*)(pre + 256))[jown];   // C1 quad
            const float gi = SI + pD.x;
            const float gf = SF + pD.y;
            const float gG = SG + pD.z;
            const float go = SO + pD.w;
            const float cc = fsig(gf) * c1r[jj] + fsig(gi) * ftanh(gG);
            c1r[jj] = cc;
            hn[jj]  = fsig(go) * ftanh(cc);
        }
#pragma unroll
        for (int k = 0; k < 8; ++k) h1r[k] = hn[k];   // commit new h1 (regs)
    }

    // epilogue: relu(h1 @ Wfc1 + bfc1) @ Wfc2 + bfc2 (h1 sliced over quad)
    float am[16];
#pragma unroll
    for (int m = 0; m < 16; ++m) am[m] = 0.0f;
#pragma unroll 1
    for (int kk = 0; kk < 8; ++kk) {
        const float* row = Wfc1 + (size_t)(so8 + kk) * 16;
        const float4 r0 = ((const float4*)row)[0];
        const float4 r1 = ((const float4*)row)[1];
        const float4 r2 = ((const float4*)row)[2];
        const float4 r3 = ((const float4*)row)[3];
        const float hv = h1r[kk];
        am[ 0] += r0.x*hv; am[ 1] += r0.y*hv; am[ 2] += r0.z*hv; am[ 3] += r0.w*hv;
        am[ 4] += r1.x*hv; am[ 5] += r1.y*hv; am[ 6] += r1.z*hv; am[ 7] += r1.w*hv;
        am[ 8] += r2.x*hv; am[ 9] += r2.y*hv; am[10] += r2.z*hv; am[11] += r2.w*hv;
        am[12] += r3.x*hv; am[13] += r3.y*hv; am[14] += r3.z*hv; am[15] += r3.w*hv;
    }
    float acc = bfc2[0];
#pragma unroll
    for (int m = 0; m < 16; ++m) {
        float a = am[m];
        a += __shfl_xor(a, 1); a += __shfl_xor(a, 2);
        acc += fmaxf(a + bfc1[m], 0.0f) * Wfc2[m];
    }
    if (s == 0 && n < N) out[n] = acc;
}

extern "C" void kernel_launch(void* const* d_in, const int* in_sizes, int n_in,
                              void* d_out, int out_size, void* d_ws, size_t ws_size,
                              hipStream_t stream) {
    (void)n_in; (void)out_size; (void)ws_size;
    // setup_inputs() order:
    // 0 x, 1 edge_index, 2 W_fp, 3 b_fp, 4 W_g1, 5 b_g1, 6 W_g2, 7 b_g2,
    // 8 W_g3, 9 b_g3, 10 W_tp, 11 b_tp, 12 Wih0, 13 Whh0, 14 bih0, 15 bhh0,
    // 16 Wih1, 17 Whh1, 18 bih1, 19 bhh1, 20 W_fc1, 21 b_fc1, 22 W_fc2, 23 b_fc2
    const float* x    = (const float*)d_in[0];
    const float* Wtp  = (const float*)d_in[10];
    const float* btp  = (const float*)d_in[11];
    const float* Wih0 = (const float*)d_in[12];
    const float* Whh0 = (const float*)d_in[13];
    const float* bih0 = (const float*)d_in[14];
    const float* bhh0 = (const float*)d_in[15];
    const float* Wih1 = (const float*)d_in[16];
    const float* Whh1 = (const float*)d_in[17];
    const float* bih1 = (const float*)d_in[18];
    const float* bhh1 = (const float*)d_in[19];
    const float* Wfc1 = (const float*)d_in[20];
    const float* bfc1 = (const float*)d_in[21];
    const float* Wfc2 = (const float*)d_in[22];
    const float* bfc2 = (const float*)d_in[23];

    float* out = (float*)d_out;
    float* pre = (float*)d_ws;   // 384 floats (repacked per-j layout)

    const int N = in_sizes[0] / 64;

    precomp_kernel<<<1, 128, 0, stream>>>(Wih0, Wtp, btp, bih0, bhh0, bih1, bhh1, pre);
    lstm_kernel<<<(N + NPB - 1) / NPB, BS, 0, stream>>>(
        x, Whh0, Wih1, Whh1, Wfc1, bfc1, Wfc2, bfc2, pre, out, N);
}

// Round 17
// 1242.274 us; speedup vs baseline: 1.6355x; 1.0159x over previous
//
#include <hip/hip_runtime.h>

// Only the temporal (LSTM) branch of the reference reaches the output
// (h_gcn is dead). Per node:
//   xt_s = x[n, 52+s] * W_tp + b_tp          (rank-1, folded into A0/C0)
//   2-layer LSTM (H=32, T=12, torch gate order i,f,g,o)
//   out[n] = relu(h1 @ W_fc1 + b_fc1) @ W_fc2 + b_fc2
//
// v10 = v9 (quad k-split + reduce-scatter gate-finish) with the VGPR-tier
// spill fixed and latency amortized:
//   - v9 @ VGPR=128: tier-edge spill (hbm 33 MB) + 4-wave tier (occupancy
//     17%, VALUBusy 52%). Busy time 690 us matched the predicted -35%.
//   - v10: gate-major windows (16 ds_read_b128 -> 64 FMAs -> rs4) halve
//     the number of exposed-latency stalls per jj; partial liveness 16->8;
//     c-state moved to per-thread LDS columns (frees 16 regs; LDS 80 KB
//     still gives 2 blocks/CU = the VGPR-tier cap, so no occupancy cost).
//   Target VGPR 104-120 (no spill), VALUBusy 65-75%.
// Spill tell-tale: hbm_bytes >> 10 MB.
// (Resubmission: round-16 bench failed on GPU acquisition, no measurement.)

#define TSTEPS 12
#define BS 512               // 8 waves per block
#define NPB (BS / 4)         // 128 nodes per block

__device__ __forceinline__ float fsig(float x) {
    float e = __expf(-x);                      // v_exp path; e in [0, inf)
    return __builtin_amdgcn_rcpf(1.0f + e);    // 1/(1+e), ~1 ulp
}

__device__ __forceinline__ float ftanh(float x) {
    float ax = fabsf(x);
    float e = __expf(-2.0f * ax);              // in (0,1], no overflow
    float r = (1.0f - e) * __builtin_amdgcn_rcpf(1.0f + e);
    return x < 0.0f ? -r : r;
}

// Repacked fold of layer-0 input matmul + biases, per OUTPUT j:
//   ws[j*8 + {0..3}] = A0 for gates i,f,g,o of j   (A0[r]=dot(Wih0[r,:],W_tp))
//   ws[j*8 + {4..7}] = C0 for gates i,f,g,o of j   (C0[r]=dot(Wih0[r,:],b_tp)+bih0[r]+bhh0[r])
//   ws[256 + j*4 + {0..3}] = C1 gates i,f,g,o      (bih1[r]+bhh1[r])
// where r = gate*32 + j.
__global__ void precomp_kernel(const float* __restrict__ Wih0,
                               const float* __restrict__ Wtp,
                               const float* __restrict__ btp,
                               const float* __restrict__ bih0,
                               const float* __restrict__ bhh0,
                               const float* __restrict__ bih1,
                               const float* __restrict__ bhh1,
                               float* __restrict__ ws) {
    int r = threadIdx.x;   // 0..127
    if (r < 128) {
        float a = 0.0f, c = 0.0f;
#pragma unroll
        for (int k = 0; k < 16; ++k) {
            float w = Wih0[r * 16 + k];
            a += w * Wtp[k];
            c += w * btp[k];
        }
        const int g4 = r >> 5;          // gate 0..3 (i,f,g,o)
        const int j  = r & 31;          // output index
        ws[j * 8 + g4]       = a;
        ws[j * 8 + 4 + g4]   = c + bih0[r] + bhh0[r];
        ws[256 + j * 4 + g4] = bih1[r] + bhh1[r];
    }
}

__device__ __forceinline__ float dot8(const float4 a0, const float4 a1,
                                      const float h[8]) {
    return a0.x*h[0] + a0.y*h[1] + a0.z*h[2] + a0.w*h[3]
         + a1.x*h[4] + a1.y*h[5] + a1.z*h[6] + a1.w*h[7];
}

// Reduce-scatter over a quad: inputs v0..v3 (per-g partials, all lanes),
// returns sum over the 4 lanes of v_s (s = lane&3). hi2=(s&2), hi1=(s&1).
__device__ __forceinline__ float rs4(float v0, float v1, float v2, float v3,
                                     bool hi2, bool hi1) {
    float sa = hi2 ? v0 : v2;     // give away first-of-other-pair
    float ka = hi2 ? v2 : v0;     // keep first-of-own-pair (g = s&2)
    float sb = hi2 ? v1 : v3;
    float kb = hi2 ? v3 : v1;     // g = (s&2)+1
    float u0 = ka + __shfl_xor(sa, 2);
    float u1 = kb + __shfl_xor(sb, 2);
    float sc = hi1 ? u0 : u1;
    float kc = hi1 ? u1 : u0;     // g = s
    return kc + __shfl_xor(sc, 1);
}

// Layer-0 window: two gates (row offsets offA, offB) for all 4 g's.
// 16 ds_read_b128 in flight (64 VGPR), then 8 dot8 (64 FMA), then 2 rs4.
__device__ __forceinline__ void l0pair(const float* __restrict__ sW,
                                       int jj, int so8, int offA, int offB,
                                       const float h[8], bool hi2, bool hi1,
                                       float& SA, float& SB) {
    float4 a0[4], a1[4], b0[4], b1[4];
#pragma unroll
    for (int g = 0; g < 4; ++g) {
        const float* wa = &sW[(g * 8 + jj + offA) * 32 + so8];
        const float* wb = &sW[(g * 8 + jj + offB) * 32 + so8];
        a0[g] = ((const float4*)wa)[0]; a1[g] = ((const float4*)wa)[1];
        b0[g] = ((const float4*)wb)[0]; b1[g] = ((const float4*)wb)[1];
    }
    float pa[4], pb[4];
#pragma unroll
    for (int g = 0; g < 4; ++g) {
        pa[g] = dot8(a0[g], a1[g], h);
        pb[g] = dot8(b0[g], b1[g], h);
    }
    SA = rs4(pa[0], pa[1], pa[2], pa[3], hi2, hi1);
    SB = rs4(pb[0], pb[1], pb[2], pb[3], hi2, hi1);
}

// Layer-1 window: one gate (row offset off), a-part (Wih1.h0) + b-part
// (Whh1.h1) for all 4 g's. 16 loads, 8 dot8, 1 rs4.
__device__ __forceinline__ float l1gate(const float* __restrict__ sW,
                                        int jj, int so8, int off,
                                        const float h0[8], const float h1[8],
                                        bool hi2, bool hi1) {
    float4 a0[4], a1[4], b0[4], b1[4];
#pragma unroll
    for (int g = 0; g < 4; ++g) {
        const float* ax = &sW[4096 + (g * 8 + jj + off) * 32 + so8];
        const float* bx = &sW[8192 + (g * 8 + jj + off) * 32 + so8];
        a0[g] = ((const float4*)ax)[0]; a1[g] = ((const float4*)ax)[1];
        b0[g] = ((const float4*)bx)[0]; b1[g] = ((const float4*)bx)[1];
    }
    float p[4];
#pragma unroll
    for (int g = 0; g < 4; ++g)
        p[g] = dot8(a0[g], a1[g], h0) + dot8(b0[g], b1[g], h1);
    return rs4(p[0], p[1], p[2], p[3], hi2, hi1);
}

__global__ __launch_bounds__(BS) void lstm_kernel(
    const float* __restrict__ x,
    const float* __restrict__ Whh0,   // [128,32]
    const float* __restrict__ Wih1,   // [128,32]
    const float* __restrict__ Whh1,   // [128,32]
    const float* __restrict__ Wfc1,   // [32,16]
    const float* __restrict__ bfc1,   // [16]
    const float* __restrict__ Wfc2,   // [16]
    const float* __restrict__ bfc2,   // [1]
    const float* __restrict__ pre,    // [384] from precomp (repacked)
    float* __restrict__ out, int N)
{
    // 48 KB weights + 2 x 16 KB per-thread c-state columns = 80 KB.
    // 2 blocks/CU by LDS == 2 blocks/CU by the 128-VGPR tier -> free.
    __shared__ __align__(16) float sW[12288];
    __shared__ float sc0[8 * BS];     // c0, column per thread
    __shared__ float sc1[8 * BS];     // c1

    const int tid = threadIdx.x;
#pragma unroll
    for (int i = 0; i < 8; ++i) sW[i * BS + tid]        = Whh0[i * BS + tid];
#pragma unroll
    for (int i = 0; i < 8; ++i) sW[4096 + i * BS + tid] = Wih1[i * BS + tid];
#pragma unroll
    for (int i = 0; i < 8; ++i) sW[8192 + i * BS + tid] = Whh1[i * BS + tid];
#pragma unroll
    for (int jj = 0; jj < 8; ++jj) {   // own columns only, no extra sync
        sc0[jj * BS + tid] = 0.0f;
        sc1[jj * BS + tid] = 0.0f;
    }
    __syncthreads();                    // only barrier in the kernel

    const int s    = tid & 3;           // k-slice / j-group 0..3
    const int node = tid >> 2;          // 0..127 within block
    const int so8  = s * 8;             // slice base (floats)
    const bool hi2 = (s & 2) != 0;
    const bool hi1 = (s & 1) != 0;
    const int n  = blockIdx.x * NPB + node;
    const int nn = (n < N) ? n : (N > 0 ? N - 1 : 0);
    const float* xr = x + (size_t)nn * 64 + 52;   // last 12 features

    // Per-lane register state: h slices + staged new-h. c lives in LDS.
    float h0r[8], h1r[8], hn[8];
#pragma unroll
    for (int k = 0; k < 8; ++k) { h0r[k] = 0.0f; h1r[k] = 0.0f; }

#pragma unroll 1
    for (int t = 0; t < TSTEPS; ++t) {
        const float xval = xr[t];

        // ---------------- layer 0 ----------------
#pragma unroll
        for (int jj = 0; jj < 8; ++jj) {
            const int jown = so8 + jj;
            float SI, SF, SG, SO;
            l0pair(sW, jj, so8,  0, 32, h0r, hi2, hi1, SI, SF);
            __builtin_amdgcn_sched_barrier(0);
            l0pair(sW, jj, so8, 64, 96, h0r, hi2, hi1, SG, SO);
            __builtin_amdgcn_sched_barrier(0);
            // finish once per j (trans ops overlap next jj's loads)
            const float4 pA = ((const float4*)pre)[jown * 2];       // A0 quad
            const float4 pC = ((const float4*)pre)[jown * 2 + 1];   // C0 quad
            const float gi = SI + pC.x + xval * pA.x;
            const float gf = SF + pC.y + xval * pA.y;
            const float gG = SG + pC.z + xval * pA.z;
            const float go = SO + pC.w + xval * pA.w;
            const int ci = jj * BS + tid;
            const float cc = fsig(gf) * sc0[ci] + fsig(gi) * ftanh(gG);
            sc0[ci] = cc;
            hn[jj]  = fsig(go) * ftanh(cc);
        }
#pragma unroll
        for (int k = 0; k < 8; ++k) h0r[k] = hn[k];   // commit new h0 (regs)

        // ---------------- layer 1 ----------------
#pragma unroll
        for (int jj = 0; jj < 8; ++jj) {
            const int jown = so8 + jj;
            const float SI = l1gate(sW, jj, so8,  0, h0r, h1r, hi2, hi1);
            __builtin_amdgcn_sched_barrier(0);
            const float SF = l1gate(sW, jj, so8, 32, h0r, h1r, hi2, hi1);
            __builtin_amdgcn_sched_barrier(0);
            const float SG = l1gate(sW, jj, so8, 64, h0r, h1r, hi2, hi1);
            __builtin_amdgcn_sched_barrier(0);
            const float SO = l1gate(sW, jj, so8, 96, h0r, h1r, hi2, hi1);
            __builtin_amdgcn_sched_barrier(0);
            const float4 pD = ((const float4*)(pre + 256))[jown];   // C1 quad
            const float gi = SI + pD.x;
            const float gf = SF + pD.y;
            const float gG = SG + pD.z;
            const float go = SO + pD.w;
            const int ci = jj * BS + tid;
            const float cc = fsig(gf) * sc1[ci] + fsig(gi) * ftanh(gG);
            sc1[ci] = cc;
            hn[jj]  = fsig(go) * ftanh(cc);
        }
#pragma unroll
        for (int k = 0; k < 8; ++k) h1r[k] = hn[k];   // commit new h1 (regs)
    }

    // epilogue: relu(h1 @ Wfc1 + bfc1) @ Wfc2 + bfc2 (h1 sliced over quad)
    float am[16];
#pragma unroll
    for (int m = 0; m < 16; ++m) am[m] = 0.0f;
#pragma unroll 1
    for (int kk = 0; kk < 8; ++kk) {
        const float* row = Wfc1 + (size_t)(so8 + kk) * 16;
        const float4 r0 = ((const float4*)row)[0];
        const float4 r1 = ((const float4*)row)[1];
        const float4 r2 = ((const float4*)row)[2];
        const float4 r3 = ((const float4*)row)[3];
        const float hv = h1r[kk];
        am[ 0] += r0.x*hv; am[ 1] += r0.y*hv; am[ 2] += r0.z*hv; am[ 3] += r0.w*hv;
        am[ 4] += r1.x*hv; am[ 5] += r1.y*hv; am[ 6] += r1.z*hv; am[ 7] += r1.w*hv;
        am[ 8] += r2.x*hv; am[ 9] += r2.y*hv; am[10] += r2.z*hv; am[11] += r2.w*hv;
        am[12] += r3.x*hv; am[13] += r3.y*hv; am[14] += r3.z*hv; am[15] += r3.w*hv;
    }
    float acc = bfc2[0];
#pragma unroll
    for (int m = 0; m < 16; ++m) {
        float a = am[m];
        a += __shfl_xor(a, 1); a += __shfl_xor(a, 2);
        acc += fmaxf(a + bfc1[m], 0.0f) * Wfc2[m];
    }
    if (s == 0 && n < N) out[n] = acc;
}

extern "C" void kernel_launch(void* const* d_in, const int* in_sizes, int n_in,
                              void* d_out, int out_size, void* d_ws, size_t ws_size,
                              hipStream_t stream) {
    (void)n_in; (void)out_size; (void)ws_size;
    // setup_inputs() order:
    // 0 x, 1 edge_index, 2 W_fp, 3 b_fp, 4 W_g1, 5 b_g1, 6 W_g2, 7 b_g2,
    // 8 W_g3, 9 b_g3, 10 W_tp, 11 b_tp, 12 Wih0, 13 Whh0, 14 bih0, 15 bhh0,
    // 16 Wih1, 17 Whh1, 18 bih1, 19 bhh1, 20 W_fc1, 21 b_fc1, 22 W_fc2, 23 b_fc2
    const float* x    = (const float*)d_in[0];
    const float* Wtp  = (const float*)d_in[10];
    const float* btp  = (const float*)d_in[11];
    const float* Wih0 = (const float*)d_in[12];
    const float* Whh0 = (const float*)d_in[13];
    const float* bih0 = (const float*)d_in[14];
    const float* bhh0 = (const float*)d_in[15];
    const float* Wih1 = (const float*)d_in[16];
    const float* Whh1 = (const float*)d_in[17];
    const float* bih1 = (const float*)d_in[18];
    const float* bhh1 = (const float*)d_in[19];
    const float* Wfc1 = (const float*)d_in[20];
    const float* bfc1 = (const float*)d_in[21];
    const float* Wfc2 = (const float*)d_in[22];
    const float* bfc2 = (const float*)d_in[23];

    float* out = (float*)d_out;
    float* pre = (float*)d_ws;   // 384 floats (repacked per-j layout)

    const int N = in_sizes[0] / 64;

    precomp_kernel<<<1, 128, 0, stream>>>(Wih0, Wtp, btp, bih0, bhh0, bih1, bhh1, pre);
    lstm_kernel<<<(N + NPB - 1) / NPB, BS, 0, stream>>>(
        x, Whh0, Wih1, Whh1, Wfc1, bfc1, Wfc2, bfc2, pre, out, N);
}